// Round 13
// baseline (467.720 us; speedup 1.0000x reference)
//
#include <hip/hip_runtime.h>
#include <math.h>

#define PI_F 3.14159265358979323846f

typedef short bf16x8 __attribute__((ext_vector_type(8)));
typedef float f32x4  __attribute__((ext_vector_type(4)));
typedef float f32x16 __attribute__((ext_vector_type(16)));

__device__ __forceinline__ short f2bf(float f) {
    union { float f; unsigned u; } v; v.f = f;
    unsigned r = v.u + 0x7fffu + ((v.u >> 16) & 1u);
    return (short)(r >> 16);
}

__device__ __forceinline__ void gld16(const short* g, short* l) {
    __builtin_amdgcn_global_load_lds(
        (const __attribute__((address_space(1))) unsigned int*)g,
        (__attribute__((address_space(3))) unsigned int*)l, 16, 0, 0);
}

// ---------------- prep kernels ----------------

// s1in: [b][g][1024][8] bf16: ch 0..3 = x group, 4..7 = 0
__global__ __launch_bounds__(256) void prep_s1in(const float* __restrict__ x, short* __restrict__ dst) {
    int idx = blockIdx.x * 256 + threadIdx.x;
    if (idx >= 64 * 1024) return;
    int px = idx & 1023;
    int g  = (idx >> 10) & 3;
    int b  = idx >> 12;
    short v8[8];
    #pragma unroll
    for (int j = 0; j < 8; ++j) {
        float f = (j < 4) ? x[((b * 16 + g * 4 + j) << 10) + px] : 0.f;
        v8[j] = f2bf(f);
    }
    *(int4*)(dst + (size_t)idx * 8) = *(const int4*)v8;
}

// s2pad x-group: [pair][36][2816 shorts] padded-swizzled rows; ch 64..67 = x, 68..71 = 0
__global__ __launch_bounds__(256) void prep_s2x(const float* __restrict__ x, short* __restrict__ dst) {
    int idx = blockIdx.x * 256 + threadIdx.x;
    if (idx >= 128 * 1024) return;
    int px = idx & 1023, pair = idx >> 10;
    int i = pair >> 4, b = pair & 15, g = i >> 1;
    int R = px >> 5, C = px & 31;
    short v8[8];
    #pragma unroll
    for (int j = 0; j < 8; ++j) {
        float f = (j < 4) ? x[((b * 16 + g * 4 + j) << 10) + px] : 0.f;
        v8[j] = f2bf(f);
    }
    int p = ((C + 2) * 72 + 64) * 2;       // byte offset in row (16B aligned)
    p ^= ((p >> 7) & 1) << 4;              // pre-swizzle
    *(int4*)((char*)dst + ((size_t)pair * 36 + R + 2) * 5632 + p) = *(const int4*)v8;
}

// s3pad x-group: [pair][38][5632 shorts] padded-swizzled rows; ch 128..131 = x, 132..135 = 0
__global__ __launch_bounds__(256) void prep_s3x(const float* __restrict__ x, short* __restrict__ dst) {
    int idx = blockIdx.x * 256 + threadIdx.x;
    if (idx >= 128 * 1024) return;
    int px = idx & 1023, pair = idx >> 10;
    int i = pair >> 4, b = pair & 15, g = i >> 1;
    int R = px >> 5, C = px & 31;
    short v8[8];
    #pragma unroll
    for (int j = 0; j < 8; ++j) {
        float f = (j < 4) ? x[((b * 16 + g * 4 + j) << 10) + px] : 0.f;
        v8[j] = f2bf(f);
    }
    int p = ((C + 3) * 136 + 128) * 2;
    p ^= ((p >> 7) & 1) << 4;
    *(int4*)((char*)dst + ((size_t)pair * 38 + R + 3) * 11264 + p) = *(const int4*)v8;
}

// weights [8][COUT][CINR][KS*KS] fp32 -> dense-K layout [8][kh][chunk][COUT][32] bf16
template<int KS, int CHS, int CINR, int COUT, int NCH>
__global__ __launch_bounds__(256) void wprep_d(const float* __restrict__ w, short* __restrict__ Bw) {
    constexpr int TOTAL = 8 * KS * NCH * COUT * 4;
    int idx = blockIdx.x * 256 + threadIdx.x;
    if (idx >= TOTAL) return;
    int kb = idx & 3;
    int r  = idx >> 2;
    int n  = r % COUT;  r /= COUT;
    int c  = r % NCH;   r /= NCH;
    int kh = r % KS;
    int br = r / KS;
    short v8[8];
    #pragma unroll
    for (int j = 0; j < 8; ++j) {
        int k   = c * 32 + kb * 8 + j;
        int kwc = k / CHS;
        int ch  = k - kwc * CHS;
        float f = (kwc < KS && ch < CINR)
                ? w[(((size_t)br * COUT + n) * CINR + ch) * (KS * KS) + kh * KS + kwc] : 0.f;
        v8[j] = f2bf(f);
    }
    *(int4*)(Bw + (size_t)idx * 8) = *(const int4*)v8;
}

// wprep7c: coalesced w7 repack (LDS-staged, contiguous reads + 128B-run writes)
__global__ __launch_bounds__(256) void wprep7c(const float* __restrict__ w, short* __restrict__ Bw) {
    __shared__ float lds[12936];
    const int t = threadIdx.x;
    const int pairN = blockIdx.x & 127;
    const int br    = blockIdx.x >> 7;
    const int n0 = pairN * 2;
    const float* src = w + ((size_t)br * 256 + n0) * 6468;
    for (int e = t; e < 3234; e += 256)
        *(float4*)(lds + e * 4) = *(const float4*)(src + e * 4);
    __syncthreads();
    for (int e = t; e < 1680; e += 256) {
        int oct = e & 3;
        int r = e >> 2;
        int c  = r % 30; r /= 30;
        int kh = r % 7;
        int dn = r / 7;
        short v8[8];
        #pragma unroll
        for (int j = 0; j < 8; ++j) {
            int k = c * 32 + oct * 8 + j;
            int kwc = k / 136, ch = k - kwc * 136;
            float f = (kwc < 7 && ch < 132) ? lds[dn * 6468 + ch * 49 + kh * 7 + kwc] : 0.f;
            v8[j] = f2bf(f);
        }
        size_t dst = ((((size_t)br * 7 + kh) * 30 + c) * 256 + (n0 + dn)) * 32 + oct * 8;
        *(int4*)(Bw + dst) = *(const int4*)v8;
    }
}

// ---------------- conv3: 16x16 path, POUT -> s2pad ----------------
template<int KS, int CHS, int COUT, int FOFF, bool S1SRC>
__global__ __launch_bounds__(512, 2) void conv_hk(
    const short* __restrict__ sIn,
    short* __restrict__ sOut,          // s2pad [pair][36][2816]
    const short* __restrict__ Bw,
    const float* __restrict__ bias,
    float* __restrict__ sums)
{
    constexpr int PAD    = KS / 2;
    constexpr int NCH    = (KS * CHS + 31) / 32;
    constexpr int TCX    = 32 + (NCH * 32 - 1) / CHS;
    constexpr int NSLOT  = 9;
    constexpr int NFN    = COUT / 64;
    constexpr int CPP    = CHS / 8;
    constexpr int RCHK   = TCX * CPP;
    constexpr int CHUNKB = COUT * 32;
    static_assert(NCH == 1, "conv3 path");

    __shared__ int4 AtileV[(NSLOT * TCX * CHS) / 8];
    short* Atile = (short*)AtileV;

    const int t    = threadIdx.x;
    const int lane = t & 63, w = t >> 6;
    const int wm = w >> 2, wn = w & 3;
    const int lm = lane & 15, kb = lane >> 4;

    const int bid = blockIdx.x;
    const int i  = bid & 7;
    const int b  = (bid >> 3) & 15;
    const int mt = bid >> 7;
    const int r0 = mt * 8;

    const int pairIdx = i * 16 + b;
    const int srcPx  = S1SRC ? ((b * 4 + (i >> 1)) << 10) : (pairIdx << 10);

    int nIdx[NFN], nOff[NFN];
    #pragma unroll
    for (int fn = 0; fn < NFN; ++fn) {
        nIdx[fn] = wn * (COUT / 4) + fn * 16 + lm;
        nOff[fn] = nIdx[fn] * 32 + kb * 8;
    }

    f32x4 acc[8][NFN];
    #pragma unroll
    for (int fm = 0; fm < 8; ++fm)
        #pragma unroll
        for (int fn = 0; fn < NFN; ++fn)
            acc[fm][fn] = (f32x4){0.f, 0.f, 0.f, 0.f};

    const short* Bp = Bw + (size_t)i * KS * NCH * CHUNKB;
    bf16x8 b0[NFN];
    #pragma unroll
    for (int fn = 0; fn < NFN; ++fn)
        b0[fn] = *(const bf16x8*)(Bp + nOff[fn]);

    for (int e = t; e < 9 * RCHK; e += 512) {
        int j  = e / RCHK, e2 = e - j * RCHK;
        int tc = e2 / CPP, kc = e2 - tc * CPP;
        int rin = r0 - PAD + j, cin = tc - PAD;
        int4 v = {0, 0, 0, 0};
        if (rin >= 0 && rin < 32 && cin >= 0 && cin < 32)
            v = *(const int4*)(sIn + (size_t)(srcPx + rin * 32 + cin) * CHS + kc * 8);
        *(int4*)(Atile + (j * TCX + tc) * CHS + kc * 8) = v;
    }
    __syncthreads();

    int aB[8];
    for (int kh = 0; kh < KS; ++kh) {
        #pragma unroll
        for (int fm = 0; fm < 8; ++fm) {
            int slot = kh + wm * 4 + (fm >> 1);
            if (slot >= NSLOT) slot -= NSLOT;
            aB[fm] = (slot * TCX + (fm & 1) * 16 + lm) * CHS + kb * 8;
        }

        const bool doStage = (kh <= KS - 3);
        const int stRin = r0 - PAD + kh + 9;
        int4 stg0 = {0, 0, 0, 0};
        if (doStage && t < RCHK) {
            int tc = t / CPP, kc = t - tc * CPP;
            int cin = tc - PAD;
            if (stRin >= 0 && stRin < 32 && cin >= 0 && cin < 32)
                stg0 = *(const int4*)(sIn + (size_t)(srcPx + stRin * 32 + cin) * CHS + kc * 8);
        }

        __builtin_amdgcn_s_setprio(1);
        #pragma unroll
        for (int fm = 0; fm < 8; ++fm) {
            bf16x8 af = *(const bf16x8*)(Atile + aB[fm]);
            #pragma unroll
            for (int fn = 0; fn < NFN; ++fn)
                acc[fm][fn] = __builtin_amdgcn_mfma_f32_16x16x32_bf16(af, b0[fn], acc[fm][fn], 0, 0, 0);
        }
        __builtin_amdgcn_s_setprio(0);
        if (kh < KS - 1) {
            #pragma unroll
            for (int fn = 0; fn < NFN; ++fn)
                b0[fn] = *(const bf16x8*)(Bp + CHUNKB + nOff[fn]);
        }
        Bp += CHUNKB;

        __syncthreads();
        if (doStage && t < RCHK) {
            int tc = t / CPP, kc = t - tc * CPP;
            *(int4*)(Atile + (kh * TCX + tc) * CHS + kc * 8) = stg0;
        }
    }

    float cwv[2][4];
    #pragma unroll
    for (int half = 0; half < 2; ++half)
        #pragma unroll
        for (int r = 0; r < 4; ++r)
            cwv[half][r] = cosf(PI_F * (half * 16 + kb * 4 + r + 0.5f) / 32.f);

    #pragma unroll
    for (int fn = 0; fn < NFN; ++fn) {
        int n = nIdx[fn];
        float bv = bias[i * COUT + n];
        float s0 = 0.f, s1 = 0.f;
        #pragma unroll
        for (int fm = 0; fm < 8; ++fm) {
            int imgrow = wm * 4 + (fm >> 1);
            int half = fm & 1;
            #pragma unroll
            for (int r = 0; r < 4; ++r) {
                float v = fmaxf(acc[fm][fn][r] + bv, 0.f);
                int col = half * 16 + kb * 4 + r;
                int R = r0 + imgrow;
                int p = ((col + 2) * 72 + n) * 2;
                p ^= ((p >> 7) & 1) << 4;
                *(short*)((char*)sOut + ((size_t)pairIdx * 36 + R + 2) * 5632 + p) = f2bf(v);
                s0 += v;
                s1 += v * cwv[half][r];
            }
        }
        s0 += __shfl_xor(s0, 16); s1 += __shfl_xor(s1, 16);
        s0 += __shfl_xor(s0, 32); s1 += __shfl_xor(s1, 32);
        if (kb == 0) {
            int ch = i * 448 + FOFF + n;
            atomicAdd(&sums[((size_t)b * 3584 + ch) * 2 + 0], s0);
            atomicAdd(&sums[((size_t)b * 3584 + ch) * 2 + 1], s1);
        }
    }
}

// ---------------- conv5: kh-fused, barrier-free (conv7 pattern) ----------------
// 8 waves = 2 Mg(8 rows) x 4 ns(32 couts); acc[8] f32x16. 20 input rows staged flat.
__global__ __launch_bounds__(512, 2) void conv5_fused(
    const short* __restrict__ s2pad,  // [128][36][2816] shorts, pre-swizzled rows
    short* __restrict__ s3pad,        // [128][38][5632] shorts, pre-swizzled rows
    const short* __restrict__ Bw,     // [8][5][12][128][32]
    const float* __restrict__ bias,   // [8][128]
    float* __restrict__ sums)
{
    constexpr int NCH = 12, COUT = 128;
    constexpr int RS2 = 2816;                  // shorts per s2pad row (5632 B)
    constexpr int CHUNKB = COUT * 32;

    __shared__ int4 AldsV[(20 * RS2) / 8];     // 112,640 B
    short* Alds = (short*)AldsV;

    const int t = threadIdx.x;
    const int lane = t & 63, w = t >> 6;
    const int Mg = w >> 2, ns = w & 3;
    const int ln = lane & 31, hi = lane >> 5;

    const int bid = blockIdx.x;
    const int i  = bid & 7;
    const int b  = (bid >> 3) & 15;
    const int mt = bid >> 7;                   // 0..1 (16 rows each)
    const int pairIdx = i * 16 + b;

    const int n = ns * 32 + ln;
    const int nOffB = n * 32 + hi * 8;

    f32x16 acc[8];
    #pragma unroll
    for (int d = 0; d < 8; ++d) acc[d] = (f32x16)(0.f);

    const short* BpI = Bw + (size_t)i * 5 * NCH * CHUNKB;
    bf16x8 bA[5], bB[5];
    #pragma unroll
    for (int kh = 0; kh < 5; ++kh)
        bA[kh] = *(const bf16x8*)(BpI + (size_t)kh * NCH * CHUNKB + nOffB);

    // stage 20 contiguous rows (mt*16 .. mt*16+19) flat into LDS
    const short* src = s2pad + ((size_t)pairIdx * 36 + mt * 16) * RS2;
    for (int s = w; s < 110; s += 8)
        gld16(src + s * 512 + lane * 8, Alds + s * 512 + lane * 8);
    __syncthreads();   // vmcnt(0): rows + B preload complete

    const char* Abase = (const char*)Alds + Mg * 8 * 5632;

    auto HALF = [&](bf16x8 (&bq)[5], int c, int kk) {
        int swb = ln * 144 + c * 64 + kk * 32 + hi * 16;
        swb ^= ((swb >> 7) & 1) << 4;
        #pragma unroll
        for (int jp = 0; jp < 12; ++jp) {
            bf16x8 af = *(const bf16x8*)(Abase + jp * 5632 + swb);
            const int klo = (jp > 7) ? (jp - 7) : 0;
            const int khi = (jp < 4) ? jp : 4;
            #pragma unroll
            for (int kh = klo; kh <= khi; ++kh)
                acc[jp - kh] = __builtin_amdgcn_mfma_f32_32x32x16_bf16(af, bq[kh], acc[jp - kh], 0, 0, 0);
        }
    };

    #pragma unroll 1
    for (int c = 0; c < NCH; ++c) {
        #pragma unroll
        for (int kh = 0; kh < 5; ++kh)
            bB[kh] = *(const bf16x8*)(BpI + ((size_t)kh * NCH + c) * CHUNKB + nOffB + 16);
        HALF(bA, c, 0);
        if (c + 1 < NCH) {
            #pragma unroll
            for (int kh = 0; kh < 5; ++kh)
                bA[kh] = *(const bf16x8*)(BpI + ((size_t)kh * NCH + c + 1) * CHUNKB + nOffB);
        }
        HALF(bB, c, 1);
    }

    // epilogue: C/D 32x32: cout = lane&31, px = (r&3)+8*(r>>2)+4*hi
    float cw[16];
    #pragma unroll
    for (int r = 0; r < 16; ++r) {
        int px = (r & 3) + 8 * (r >> 2) + 4 * hi;
        cw[r] = cosf(PI_F * (px + 0.5f) / 32.f);
    }

    float bv = bias[i * COUT + n];
    float s0 = 0.f, s1 = 0.f;
    #pragma unroll
    for (int d = 0; d < 8; ++d) {
        int R = mt * 16 + Mg * 8 + d;
        #pragma unroll
        for (int r = 0; r < 16; ++r) {
            float v = fmaxf(acc[d][r] + bv, 0.f);
            int px = (r & 3) + 8 * (r >> 2) + 4 * hi;
            int p = ((px + 3) * 136 + n) * 2;
            p ^= ((p >> 7) & 1) << 4;
            *(short*)((char*)s3pad + ((size_t)pairIdx * 38 + R + 3) * 11264 + p) = f2bf(v);
            s0 += v;
            s1 += v * cw[r];
        }
    }
    s0 += __shfl_xor(s0, 32);
    s1 += __shfl_xor(s1, 32);
    if (hi == 0) {
        int ch = i * 448 + 64 + n;
        atomicAdd(&sums[((size_t)b * 3584 + ch) * 2 + 0], s0);
        atomicAdd(&sums[((size_t)b * 3584 + ch) * 2 + 1], s1);
    }
}

// ---------------- conv7: input-row-stationary, kh-fused (round-10, 70% MfmaUtil) ----------------
__global__ __launch_bounds__(512, 2) void conv7_fused(
    const short* __restrict__ sPad,   // [128][38][5632] shorts, pre-swizzled rows
    const short* __restrict__ Bw,     // [8][7][30][256][32]
    const float* __restrict__ bias,   // [8][256]
    float* __restrict__ sums)
{
    constexpr int NCH = 30, COUT = 256;
    constexpr int RSTR = 5632;
    constexpr int CHUNKB = COUT * 32;

    __shared__ int4 AldsV[(14 * RSTR) / 8];    // 157,696 B
    short* Alds = (short*)AldsV;

    const int t    = threadIdx.x;
    const int lane = t & 63, w = t >> 6;
    const int ln = lane & 31, hi = lane >> 5;

    const int bid = blockIdx.x;
    const int i  = bid & 7;
    const int b  = (bid >> 3) & 15;
    const int mt = bid >> 7;
    const int r0 = mt * 8;
    const size_t sBase = (size_t)(i * 16 + b) * 38 * RSTR;

    const int n = w * 32 + ln;
    const int nOffB = n * 32 + hi * 8;

    f32x16 acc[8];
    #pragma unroll
    for (int ro = 0; ro < 8; ++ro) acc[ro] = (f32x16)(0.f);

    const short* BpI = Bw + (size_t)i * 7 * NCH * CHUNKB;

    for (int s = w; s < 154; s += 8) {
        int j = s / 11, sg = s - j * 11;
        gld16(sPad + sBase + (size_t)(r0 + j) * RSTR + sg * 512 + lane * 8,
              Alds + j * RSTR + sg * 512 + lane * 8);
    }
    bf16x8 bA[7], bB[7];
    #pragma unroll
    for (int kh = 0; kh < 7; ++kh)
        bA[kh] = *(const bf16x8*)(BpI + (size_t)kh * NCH * CHUNKB + nOffB);
    __syncthreads();

    auto HALF = [&](bf16x8 (&bq)[7], int c, int kk) {
        int swb = ln * 272 + c * 64 + kk * 32 + hi * 16;
        swb ^= ((swb >> 7) & 1) << 4;
        #pragma unroll
        for (int j = 0; j < 14; ++j) {
            bf16x8 af = *(const bf16x8*)((const char*)Alds + j * 11264 + swb);
            const int klo = (j > 7) ? (j - 7) : 0;
            const int khi = (j < 6) ? j : 6;
            #pragma unroll
            for (int kh = klo; kh <= khi; ++kh)
                acc[j - kh] = __builtin_amdgcn_mfma_f32_32x32x16_bf16(af, bq[kh], acc[j - kh], 0, 0, 0);
        }
    };

    #pragma unroll 1
    for (int c = 0; c < NCH; ++c) {
        #pragma unroll
        for (int kh = 0; kh < 7; ++kh)
            bB[kh] = *(const bf16x8*)(BpI + ((size_t)kh * NCH + c) * CHUNKB + nOffB + 16);
        HALF(bA, c, 0);
        if (c + 1 < NCH) {
            #pragma unroll
            for (int kh = 0; kh < 7; ++kh)
                bA[kh] = *(const bf16x8*)(BpI + ((size_t)kh * NCH + c + 1) * CHUNKB + nOffB);
        }
        HALF(bB, c, 1);
    }

    float cw[16];
    #pragma unroll
    for (int r = 0; r < 16; ++r) {
        int px = (r & 3) + 8 * (r >> 2) + 4 * hi;
        cw[r] = cosf(PI_F * (px + 0.5f) / 32.f);
    }

    float bv = bias[i * COUT + n];
    float s0 = 0.f, s1 = 0.f;
    #pragma unroll
    for (int ro = 0; ro < 8; ++ro) {
        #pragma unroll
        for (int r = 0; r < 16; ++r) {
            float v = fmaxf(acc[ro][r] + bv, 0.f);
            s0 += v;
            s1 += v * cw[r];
        }
    }
    s0 += __shfl_xor(s0, 32);
    s1 += __shfl_xor(s1, 32);
    if (hi == 0) {
        int ch = i * 448 + 192 + n;
        atomicAdd(&sums[((size_t)b * 3584 + ch) * 2 + 0], s0);
        atomicAdd(&sums[((size_t)b * 3584 + ch) * 2 + 1], s1);
    }
}

// ---------------- head: LN stats + parallel GEMV ----------------
__global__ __launch_bounds__(256) void ln_stats(const float* __restrict__ sums,
                                                float* __restrict__ stats) {
    __shared__ float red[8];
    const int b = blockIdx.x;
    const int t = threadIdx.x, lane = t & 63, wv = t >> 6;
    const float* S = sums + (size_t)b * 7168;
    float ls = 0.f, lq = 0.f;
    for (int f = t; f < 7168; f += 256) { float v = S[f]; ls += v; lq += v * v; }
    for (int m = 1; m < 64; m <<= 1) { ls += __shfl_xor(ls, m); lq += __shfl_xor(lq, m); }
    if (lane == 0) { red[wv] = ls; red[4 + wv] = lq; }
    __syncthreads();
    if (t == 0) {
        float ts = red[0] + red[1] + red[2] + red[3];
        float tq = red[4] + red[5] + red[6] + red[7];
        float mu  = ts * (1.f / 7168.f);
        float var = tq * (1.f / 7168.f) - mu * mu;
        stats[b * 2 + 0] = mu;
        stats[b * 2 + 1] = rsqrtf(var + 1e-5f);
    }
}

__global__ __launch_bounds__(256) void head_gemv(
    const float* __restrict__ sums,
    const float* __restrict__ stats,
    const float* __restrict__ Wg, const float* __restrict__ bg,
    const float* __restrict__ gamma, const float* __restrict__ beta,
    const float* __restrict__ Wd, const float* __restrict__ bd,
    float* __restrict__ out)
{
    __shared__ float red[8];
    const int n = blockIdx.x % 60;
    const int b = blockIdx.x / 60;
    const int t = threadIdx.x, lane = t & 63, wv = t >> 6;
    const float* S  = sums + (size_t)b * 7168;
    const float mu  = stats[b * 2 + 0];
    const float inv = stats[b * 2 + 1];

    const float* wd = Wd + (size_t)n * 7168;
    float accd = 0.f;
    for (int f = t; f < 7168; f += 256) {
        float v = (S[f] - mu) * inv * gamma[f] + beta[f];
        accd = fmaf(v, wd[f], accd);
    }
    const float* wg = Wg + (size_t)n * 3584;
    float accg = 0.f;
    for (int ch = t; ch < 3584; ch += 256)
        accg = fmaf(S[2 * ch], wg[ch], accg);

    for (int m = 1; m < 64; m <<= 1) { accg += __shfl_xor(accg, m); accd += __shfl_xor(accd, m); }
    if (lane == 0) { red[wv] = accg; red[4 + wv] = accd; }
    __syncthreads();
    if (t == 0) {
        float g = red[0] + red[1] + red[2] + red[3];
        float d = red[4] + red[5] + red[6] + red[7];
        out[b * 60 + n]       = g * (1.f / 1024.f) + bg[n];
        out[960 + b * 60 + n] = d + bd[n];
    }
}

extern "C" void kernel_launch(void* const* d_in, const int* in_sizes, int n_in,
                              void* d_out, int out_size, void* d_ws, size_t ws_size,
                              hipStream_t stream)
{
    const float* x     = (const float*)d_in[0];
    const float* w3    = (const float*)d_in[1];
    const float* b3    = (const float*)d_in[2];
    const float* w5    = (const float*)d_in[3];
    const float* b5    = (const float*)d_in[4];
    const float* w7    = (const float*)d_in[5];
    const float* b7    = (const float*)d_in[6];
    const float* Wg    = (const float*)d_in[7];
    const float* bg    = (const float*)d_in[8];
    const float* gamma = (const float*)d_in[9];
    const float* beta  = (const float*)d_in[10];
    const float* Wd    = (const float*)d_in[11];
    const float* bd    = (const float*)d_in[12];
    float* out = (float*)d_out;

    // workspace layout (bytes). s2pad and Bw7 TIME-ALIAS the same region:
    // s2pad is dead after conv5; wprep7c (launched after conv5) rewrites it as Bw7.
    char* p = (char*)d_ws;
    float* sums  = (float*)p;             p += 458752;      // 16*3584*2 f32
    float* stats = (float*)p;             p += 128;
    short* s1in  = (short*)p;             p += 1048576;     // [64][1024][8]
    short* s2pad = (short*)p;                               // [128][36][2816] (25.95 MB)
    short* Bw7   = (short*)p;             p += 27525120;    // [8][7][30][256][32] (27.5 MB)
    short* s3pad = (short*)p;             p += 54788096;    // [128][38][5632]
    short* Bw3   = (short*)p;             p += 98304;       // [8][3][1][64][32]
    short* Bw5   = (short*)p;             p += 3932160;     // [8][5][12][128][32]

    hipMemsetAsync(sums, 0, 458752, stream);
    hipMemsetAsync(s2pad, 0, 25952256, stream);
    hipMemsetAsync(s3pad, 0, 54788096, stream);
    prep_s1in<<<dim3(256), dim3(256), 0, stream>>>(x, s1in);
    prep_s2x<<<dim3(512), dim3(256), 0, stream>>>(x, s2pad);
    prep_s3x<<<dim3(512), dim3(256), 0, stream>>>(x, s3pad);
    wprep_d<3, 8, 4, 64, 1><<<dim3(24), dim3(256), 0, stream>>>(w3, Bw3);
    wprep_d<5, 72, 68, 128, 12><<<dim3(960), dim3(256), 0, stream>>>(w5, Bw5);

    conv_hk<3, 8, 64, 0, true><<<dim3(512), dim3(512), 0, stream>>>(s1in, s2pad, Bw3, b3, sums);
    conv5_fused<<<dim3(256), dim3(512), 0, stream>>>(s2pad, s3pad, Bw5, b5, sums);
    wprep7c<<<dim3(1024), dim3(256), 0, stream>>>(w7, Bw7);   // overwrites s2pad region
    conv7_fused<<<dim3(512), dim3(512), 0, stream>>>(s3pad, Bw7, b7, sums);

    ln_stats<<<dim3(16), dim3(256), 0, stream>>>(sums, stats);
    head_gemv<<<dim3(960), dim3(256), 0, stream>>>(sums, stats, Wg, bg, gamma, beta, Wd, bd, out);
}

// Round 14
// 449.923 us; speedup vs baseline: 1.0396x; 1.0396x over previous
//
#include <hip/hip_runtime.h>
#include <math.h>

#define PI_F 3.14159265358979323846f

typedef short bf16x8 __attribute__((ext_vector_type(8)));
typedef float f32x4  __attribute__((ext_vector_type(4)));
typedef float f32x16 __attribute__((ext_vector_type(16)));

__device__ __forceinline__ short f2bf(float f) {
    union { float f; unsigned u; } v; v.f = f;
    unsigned r = v.u + 0x7fffu + ((v.u >> 16) & 1u);
    return (short)(r >> 16);
}

__device__ __forceinline__ void gld16(const short* g, short* l) {
    __builtin_amdgcn_global_load_lds(
        (const __attribute__((address_space(1))) unsigned int*)g,
        (__attribute__((address_space(3))) unsigned int*)l, 16, 0, 0);
}

// ---------------- prep kernels ----------------

// s1in: [b][g][1024][8] bf16: ch 0..3 = x group, 4..7 = 0
__global__ __launch_bounds__(256) void prep_s1in(const float* __restrict__ x, short* __restrict__ dst) {
    int idx = blockIdx.x * 256 + threadIdx.x;
    if (idx >= 64 * 1024) return;
    int px = idx & 1023;
    int g  = (idx >> 10) & 3;
    int b  = idx >> 12;
    short v8[8];
    #pragma unroll
    for (int j = 0; j < 8; ++j) {
        float f = (j < 4) ? x[((b * 16 + g * 4 + j) << 10) + px] : 0.f;
        v8[j] = f2bf(f);
    }
    *(int4*)(dst + (size_t)idx * 8) = *(const int4*)v8;
}

// s2in x-group: [pair][1024][72] bf16 at ch 64..71
__global__ __launch_bounds__(256) void prep_sx(const float* __restrict__ x, short* __restrict__ dst,
                                               int CHS, int CH0) {
    int idx = blockIdx.x * 256 + threadIdx.x;
    if (idx >= 128 * 1024) return;
    int px = idx & 1023, pair = idx >> 10;
    int i = pair >> 4, b = pair & 15, g = i >> 1;
    short v8[8];
    #pragma unroll
    for (int j = 0; j < 8; ++j) {
        float f = (j < 4) ? x[((b * 16 + g * 4 + j) << 10) + px] : 0.f;
        v8[j] = f2bf(f);
    }
    *(int4*)(dst + (size_t)idx * CHS + CH0) = *(const int4*)v8;
}

// s3pad x-group: padded-swizzled rows [pair][38][5632 shorts]; ch 128..131 = x, 132..135 = 0
__global__ __launch_bounds__(256) void prep_s3x(const float* __restrict__ x, short* __restrict__ dst) {
    int idx = blockIdx.x * 256 + threadIdx.x;
    if (idx >= 128 * 1024) return;
    int px = idx & 1023, pair = idx >> 10;
    int i = pair >> 4, b = pair & 15, g = i >> 1;
    int R = px >> 5, C = px & 31;
    short v8[8];
    #pragma unroll
    for (int j = 0; j < 8; ++j) {
        float f = (j < 4) ? x[((b * 16 + g * 4 + j) << 10) + px] : 0.f;
        v8[j] = f2bf(f);
    }
    int p = ((C + 3) * 136 + 128) * 2;     // byte offset in row (16B aligned)
    p ^= ((p >> 7) & 1) << 4;              // pre-swizzle
    *(int4*)((char*)dst + ((size_t)pair * 38 + R + 3) * 11264 + p) = *(const int4*)v8;
}

// weights [8][COUT][CINR][KS*KS] fp32 -> dense-K layout [8][kh][chunk][COUT][32] bf16
template<int KS, int CHS, int CINR, int COUT, int NCH>
__global__ __launch_bounds__(256) void wprep_d(const float* __restrict__ w, short* __restrict__ Bw) {
    constexpr int TOTAL = 8 * KS * NCH * COUT * 4;
    int idx = blockIdx.x * 256 + threadIdx.x;
    if (idx >= TOTAL) return;
    int kb = idx & 3;
    int r  = idx >> 2;
    int n  = r % COUT;  r /= COUT;
    int c  = r % NCH;   r /= NCH;
    int kh = r % KS;
    int br = r / KS;
    short v8[8];
    #pragma unroll
    for (int j = 0; j < 8; ++j) {
        int k   = c * 32 + kb * 8 + j;
        int kwc = k / CHS;
        int ch  = k - kwc * CHS;
        float f = (kwc < KS && ch < CINR)
                ? w[(((size_t)br * COUT + n) * CINR + ch) * (KS * KS) + kh * KS + kwc] : 0.f;
        v8[j] = f2bf(f);
    }
    *(int4*)(Bw + (size_t)idx * 8) = *(const int4*)v8;
}

// wprep7c: coalesced w7 repack (LDS-staged, contiguous reads + 128B-run writes)
__global__ __launch_bounds__(256) void wprep7c(const float* __restrict__ w, short* __restrict__ Bw) {
    __shared__ float lds[12936];
    const int t = threadIdx.x;
    const int pairN = blockIdx.x & 127;
    const int br    = blockIdx.x >> 7;
    const int n0 = pairN * 2;
    const float* src = w + ((size_t)br * 256 + n0) * 6468;
    for (int e = t; e < 3234; e += 256)
        *(float4*)(lds + e * 4) = *(const float4*)(src + e * 4);
    __syncthreads();
    for (int e = t; e < 1680; e += 256) {
        int oct = e & 3;
        int r = e >> 2;
        int c  = r % 30; r /= 30;
        int kh = r % 7;
        int dn = r / 7;
        short v8[8];
        #pragma unroll
        for (int j = 0; j < 8; ++j) {
            int k = c * 32 + oct * 8 + j;
            int kwc = k / 136, ch = k - kwc * 136;
            float f = (kwc < 7 && ch < 132) ? lds[dn * 6468 + ch * 49 + kh * 7 + kwc] : 0.f;
            v8[j] = f2bf(f);
        }
        size_t dst = ((((size_t)br * 7 + kh) * 30 + c) * 256 + (n0 + dn)) * 32 + oct * 8;
        *(int4*)(Bw + dst) = *(const int4*)v8;
    }
}

// ---------------- conv3/conv5: 16x16 path (round-12 structure, unchanged) ----------------
template<int KS, int CHS, int COUT, int CHS_OUT, int FOFF, bool S1SRC, bool POUT>
__global__ __launch_bounds__(512, 2) void conv_hk(
    const short* __restrict__ sIn,
    short* __restrict__ sOut,
    const short* __restrict__ Bw,
    const float* __restrict__ bias,
    float* __restrict__ sums)
{
    constexpr int PAD    = KS / 2;
    constexpr int NCH    = (KS * CHS + 31) / 32;
    constexpr int TCX    = 32 + (NCH * 32 - 1) / CHS;
    constexpr int NSLOT  = 9;
    constexpr int NFN    = COUT / 64;
    constexpr int CPP    = CHS / 8;
    constexpr int RCHK   = TCX * CPP;
    constexpr int CHUNKB = COUT * 32;
    static_assert(NCH == 1 || (NCH % 2) == 0, "NCH must be 1 or even");
    static_assert(RCHK <= 512, "single stg reg");

    __shared__ int4 AtileV[(NSLOT * TCX * CHS) / 8];
    short* Atile = (short*)AtileV;

    const int t    = threadIdx.x;
    const int lane = t & 63, w = t >> 6;
    const int wm = w >> 2, wn = w & 3;
    const int lm = lane & 15, kb = lane >> 4;

    const int bid = blockIdx.x;
    const int i  = bid & 7;
    const int b  = (bid >> 3) & 15;
    const int mt = bid >> 7;
    const int r0 = mt * 8;

    const int pairIdx = i * 16 + b;
    const int pairPx = pairIdx << 10;
    const int srcPx  = S1SRC ? ((b * 4 + (i >> 1)) << 10) : pairPx;

    int nIdx[NFN], nOff[NFN];
    #pragma unroll
    for (int fn = 0; fn < NFN; ++fn) {
        nIdx[fn] = wn * (COUT / 4) + fn * 16 + lm;
        nOff[fn] = nIdx[fn] * 32 + kb * 8;
    }

    f32x4 acc[8][NFN];
    #pragma unroll
    for (int fm = 0; fm < 8; ++fm)
        #pragma unroll
        for (int fn = 0; fn < NFN; ++fn)
            acc[fm][fn] = (f32x4){0.f, 0.f, 0.f, 0.f};

    const short* Bp = Bw + (size_t)i * KS * NCH * CHUNKB;
    bf16x8 b0[NFN], b1[NFN];
    #pragma unroll
    for (int fn = 0; fn < NFN; ++fn)
        b0[fn] = *(const bf16x8*)(Bp + nOff[fn]);

    for (int e = t; e < 9 * RCHK; e += 512) {
        int j  = e / RCHK, e2 = e - j * RCHK;
        int tc = e2 / CPP, kc = e2 - tc * CPP;
        int rin = r0 - PAD + j, cin = tc - PAD;
        int4 v = {0, 0, 0, 0};
        if (rin >= 0 && rin < 32 && cin >= 0 && cin < 32)
            v = *(const int4*)(sIn + (size_t)(srcPx + rin * 32 + cin) * CHS + kc * 8);
        *(int4*)(Atile + (j * TCX + tc) * CHS + kc * 8) = v;
    }
    __syncthreads();

    int aB[8];

    for (int kh = 0; kh < KS; ++kh) {
        #pragma unroll
        for (int fm = 0; fm < 8; ++fm) {
            int slot = kh + wm * 4 + (fm >> 1);
            if (slot >= NSLOT) slot -= NSLOT;
            aB[fm] = (slot * TCX + (fm & 1) * 16 + lm) * CHS + kb * 8;
        }

        const bool doStage = (kh <= KS - 3);
        const int stRin = r0 - PAD + kh + 9;
        int4 stg0 = {0, 0, 0, 0};
        if (doStage) {
            if (t < RCHK) {
                int tc = t / CPP, kc = t - tc * CPP;
                int cin = tc - PAD;
                if (stRin >= 0 && stRin < 32 && cin >= 0 && cin < 32)
                    stg0 = *(const int4*)(sIn + (size_t)(srcPx + stRin * 32 + cin) * CHS + kc * 8);
            }
        }

        if constexpr (NCH == 1) {
            __builtin_amdgcn_s_setprio(1);
            #pragma unroll
            for (int fm = 0; fm < 8; ++fm) {
                bf16x8 af = *(const bf16x8*)(Atile + aB[fm]);
                #pragma unroll
                for (int fn = 0; fn < NFN; ++fn)
                    acc[fm][fn] = __builtin_amdgcn_mfma_f32_16x16x32_bf16(af, b0[fn], acc[fm][fn], 0, 0, 0);
            }
            __builtin_amdgcn_s_setprio(0);
            if (kh < KS - 1) {
                #pragma unroll
                for (int fn = 0; fn < NFN; ++fn)
                    b0[fn] = *(const bf16x8*)(Bp + CHUNKB + nOff[fn]);
            }
            Bp += CHUNKB;
        } else {
            #pragma unroll 1
            for (int c = 0; c < NCH; c += 2) {
                #pragma unroll
                for (int fn = 0; fn < NFN; ++fn)
                    b1[fn] = *(const bf16x8*)(Bp + (size_t)(c + 1) * CHUNKB + nOff[fn]);
                __builtin_amdgcn_s_setprio(1);
                #pragma unroll
                for (int fm = 0; fm < 8; ++fm) {
                    bf16x8 af = *(const bf16x8*)(Atile + aB[fm] + c * 32);
                    #pragma unroll
                    for (int fn = 0; fn < NFN; ++fn)
                        acc[fm][fn] = __builtin_amdgcn_mfma_f32_16x16x32_bf16(af, b0[fn], acc[fm][fn], 0, 0, 0);
                }
                __builtin_amdgcn_s_setprio(0);
                if (!(kh == KS - 1 && c + 2 >= NCH)) {
                    #pragma unroll
                    for (int fn = 0; fn < NFN; ++fn)
                        b0[fn] = *(const bf16x8*)(Bp + (size_t)(c + 2) * CHUNKB + nOff[fn]);
                }
                __builtin_amdgcn_s_setprio(1);
                #pragma unroll
                for (int fm = 0; fm < 8; ++fm) {
                    bf16x8 af = *(const bf16x8*)(Atile + aB[fm] + (c + 1) * 32);
                    #pragma unroll
                    for (int fn = 0; fn < NFN; ++fn)
                        acc[fm][fn] = __builtin_amdgcn_mfma_f32_16x16x32_bf16(af, b1[fn], acc[fm][fn], 0, 0, 0);
                }
                __builtin_amdgcn_s_setprio(0);
            }
            Bp += (size_t)NCH * CHUNKB;
        }

        __syncthreads();
        if (doStage && t < RCHK) {
            int tc = t / CPP, kc = t - tc * CPP;
            *(int4*)(Atile + (kh * TCX + tc) * CHS + kc * 8) = stg0;
        }
    }

    float cwv[2][4];
    #pragma unroll
    for (int half = 0; half < 2; ++half)
        #pragma unroll
        for (int r = 0; r < 4; ++r)
            cwv[half][r] = cosf(PI_F * (half * 16 + kb * 4 + r + 0.5f) / 32.f);

    #pragma unroll
    for (int fn = 0; fn < NFN; ++fn) {
        int n = nIdx[fn];
        float bv = bias[i * COUT + n];
        float s0 = 0.f, s1 = 0.f;
        #pragma unroll
        for (int fm = 0; fm < 8; ++fm) {
            int imgrow = wm * 4 + (fm >> 1);
            int half = fm & 1;
            #pragma unroll
            for (int r = 0; r < 4; ++r) {
                float v = fmaxf(acc[fm][fn][r] + bv, 0.f);
                int col = half * 16 + kb * 4 + r;
                int R = r0 + imgrow;
                if constexpr (POUT) {
                    int p = ((col + 3) * CHS_OUT + n) * 2;
                    p ^= ((p >> 7) & 1) << 4;
                    *(short*)((char*)sOut + ((size_t)pairIdx * 38 + R + 3) * 11264 + p) = f2bf(v);
                } else if constexpr (CHS_OUT > 0) {
                    sOut[(size_t)(pairPx + R * 32 + col) * CHS_OUT + n] = f2bf(v);
                }
                s0 += v;
                s1 += v * cwv[half][r];
            }
        }
        s0 += __shfl_xor(s0, 16); s1 += __shfl_xor(s1, 16);
        s0 += __shfl_xor(s0, 32); s1 += __shfl_xor(s1, 32);
        if (kb == 0) {
            int ch = i * 448 + FOFF + n;
            atomicAdd(&sums[((size_t)b * 3584 + ch) * 2 + 0], s0);
            atomicAdd(&sums[((size_t)b * 3584 + ch) * 2 + 1], s1);
        }
    }
}

// ---------------- conv7: kh-fused + wave-desync + setprio ----------------
// Round-10 structure (8 waves, acc[8], barrier-free) with two additions:
// (1) waves with w&4 (SIMD-sharing partners) traverse K-chunks starting at c=15
//     (commutative accumulation -> any order), so co-resident waves are in
//     complementary MFMA/load phases instead of lockstep;
// (2) s_setprio(1) around each 56-MFMA HALF (role diversity now exists).
__global__ __launch_bounds__(512, 2) void conv7_fused(
    const short* __restrict__ sPad,   // [128][38][5632] shorts, pre-swizzled rows
    const short* __restrict__ Bw,     // [8][7][30][256][32]
    const float* __restrict__ bias,   // [8][256]
    float* __restrict__ sums)
{
    constexpr int NCH = 30, COUT = 256;
    constexpr int RSTR = 5632;
    constexpr int CHUNKB = COUT * 32;

    __shared__ int4 AldsV[(14 * RSTR) / 8];    // 157,696 B
    short* Alds = (short*)AldsV;

    const int t    = threadIdx.x;
    const int lane = t & 63, w = t >> 6;
    const int ln = lane & 31, hi = lane >> 5;

    const int bid = blockIdx.x;
    const int i  = bid & 7;
    const int b  = (bid >> 3) & 15;
    const int mt = bid >> 7;
    const int r0 = mt * 8;
    const size_t sBase = (size_t)(i * 16 + b) * 38 * RSTR;

    const int n = w * 32 + ln;
    const int nOffB = n * 32 + hi * 8;
    const int cstart = (w & 4) ? 15 : 0;       // desync SIMD-sharing waves

    f32x16 acc[8];
    #pragma unroll
    for (int ro = 0; ro < 8; ++ro) acc[ro] = (f32x16)(0.f);

    const short* BpI = Bw + (size_t)i * 7 * NCH * CHUNKB;

    for (int s = w; s < 154; s += 8) {
        int j = s / 11, sg = s - j * 11;
        gld16(sPad + sBase + (size_t)(r0 + j) * RSTR + sg * 512 + lane * 8,
              Alds + j * RSTR + sg * 512 + lane * 8);
    }
    bf16x8 bA[7], bB[7];
    #pragma unroll
    for (int kh = 0; kh < 7; ++kh)
        bA[kh] = *(const bf16x8*)(BpI + ((size_t)kh * NCH + cstart) * CHUNKB + nOffB);
    __syncthreads();

    auto HALF = [&](bf16x8 (&bq)[7], int c, int kk) {
        int swb = ln * 272 + c * 64 + kk * 32 + hi * 16;
        swb ^= ((swb >> 7) & 1) << 4;
        __builtin_amdgcn_s_setprio(1);
        #pragma unroll
        for (int j = 0; j < 14; ++j) {
            bf16x8 af = *(const bf16x8*)((const char*)Alds + j * 11264 + swb);
            const int klo = (j > 7) ? (j - 7) : 0;
            const int khi = (j < 6) ? j : 6;
            #pragma unroll
            for (int kh = klo; kh <= khi; ++kh)
                acc[j - kh] = __builtin_amdgcn_mfma_f32_32x32x16_bf16(af, bq[kh], acc[j - kh], 0, 0, 0);
        }
        __builtin_amdgcn_s_setprio(0);
    };

    #pragma unroll 1
    for (int ci = 0; ci < NCH; ++ci) {
        int cc = cstart + ci; if (cc >= NCH) cc -= NCH;
        int cn = cc + 1;      if (cn >= NCH) cn -= NCH;
        #pragma unroll
        for (int kh = 0; kh < 7; ++kh)
            bB[kh] = *(const bf16x8*)(BpI + ((size_t)kh * NCH + cc) * CHUNKB + nOffB + 16);
        HALF(bA, cc, 0);
        if (ci + 1 < NCH) {
            #pragma unroll
            for (int kh = 0; kh < 7; ++kh)
                bA[kh] = *(const bf16x8*)(BpI + ((size_t)kh * NCH + cn) * CHUNKB + nOffB);
        }
        HALF(bB, cc, 1);
    }

    float cw[16];
    #pragma unroll
    for (int r = 0; r < 16; ++r) {
        int px = (r & 3) + 8 * (r >> 2) + 4 * hi;
        cw[r] = cosf(PI_F * (px + 0.5f) / 32.f);
    }

    float bv = bias[i * COUT + n];
    float s0 = 0.f, s1 = 0.f;
    #pragma unroll
    for (int ro = 0; ro < 8; ++ro) {
        #pragma unroll
        for (int r = 0; r < 16; ++r) {
            float v = fmaxf(acc[ro][r] + bv, 0.f);
            s0 += v;
            s1 += v * cw[r];
        }
    }
    s0 += __shfl_xor(s0, 32);
    s1 += __shfl_xor(s1, 32);
    if (hi == 0) {
        int ch = i * 448 + 192 + n;
        atomicAdd(&sums[((size_t)b * 3584 + ch) * 2 + 0], s0);
        atomicAdd(&sums[((size_t)b * 3584 + ch) * 2 + 1], s1);
    }
}

// ---------------- head: LN stats + parallel GEMV ----------------
__global__ __launch_bounds__(256) void ln_stats(const float* __restrict__ sums,
                                                float* __restrict__ stats) {
    __shared__ float red[8];
    const int b = blockIdx.x;
    const int t = threadIdx.x, lane = t & 63, wv = t >> 6;
    const float* S = sums + (size_t)b * 7168;
    float ls = 0.f, lq = 0.f;
    for (int f = t; f < 7168; f += 256) { float v = S[f]; ls += v; lq += v * v; }
    for (int m = 1; m < 64; m <<= 1) { ls += __shfl_xor(ls, m); lq += __shfl_xor(lq, m); }
    if (lane == 0) { red[wv] = ls; red[4 + wv] = lq; }
    __syncthreads();
    if (t == 0) {
        float ts = red[0] + red[1] + red[2] + red[3];
        float tq = red[4] + red[5] + red[6] + red[7];
        float mu  = ts * (1.f / 7168.f);
        float var = tq * (1.f / 7168.f) - mu * mu;
        stats[b * 2 + 0] = mu;
        stats[b * 2 + 1] = rsqrtf(var + 1e-5f);
    }
}

__global__ __launch_bounds__(256) void head_gemv(
    const float* __restrict__ sums,
    const float* __restrict__ stats,
    const float* __restrict__ Wg, const float* __restrict__ bg,
    const float* __restrict__ gamma, const float* __restrict__ beta,
    const float* __restrict__ Wd, const float* __restrict__ bd,
    float* __restrict__ out)
{
    __shared__ float red[8];
    const int n = blockIdx.x % 60;
    const int b = blockIdx.x / 60;
    const int t = threadIdx.x, lane = t & 63, wv = t >> 6;
    const float* S  = sums + (size_t)b * 7168;
    const float mu  = stats[b * 2 + 0];
    const float inv = stats[b * 2 + 1];

    const float* wd = Wd + (size_t)n * 7168;
    float accd = 0.f;
    for (int f = t; f < 7168; f += 256) {
        float v = (S[f] - mu) * inv * gamma[f] + beta[f];
        accd = fmaf(v, wd[f], accd);
    }
    const float* wg = Wg + (size_t)n * 3584;
    float accg = 0.f;
    for (int ch = t; ch < 3584; ch += 256)
        accg = fmaf(S[2 * ch], wg[ch], accg);

    for (int m = 1; m < 64; m <<= 1) { accg += __shfl_xor(accg, m); accd += __shfl_xor(accd, m); }
    if (lane == 0) { red[wv] = accg; red[4 + wv] = accd; }
    __syncthreads();
    if (t == 0) {
        float g = red[0] + red[1] + red[2] + red[3];
        float d = red[4] + red[5] + red[6] + red[7];
        out[b * 60 + n]       = g * (1.f / 1024.f) + bg[n];
        out[960 + b * 60 + n] = d + bd[n];
    }
}

extern "C" void kernel_launch(void* const* d_in, const int* in_sizes, int n_in,
                              void* d_out, int out_size, void* d_ws, size_t ws_size,
                              hipStream_t stream)
{
    const float* x     = (const float*)d_in[0];
    const float* w3    = (const float*)d_in[1];
    const float* b3    = (const float*)d_in[2];
    const float* w5    = (const float*)d_in[3];
    const float* b5    = (const float*)d_in[4];
    const float* w7    = (const float*)d_in[5];
    const float* b7    = (const float*)d_in[6];
    const float* Wg    = (const float*)d_in[7];
    const float* bg    = (const float*)d_in[8];
    const float* gamma = (const float*)d_in[9];
    const float* beta  = (const float*)d_in[10];
    const float* Wd    = (const float*)d_in[11];
    const float* bd    = (const float*)d_in[12];
    float* out = (float*)d_out;

    // workspace layout (bytes) — round-12 proven layout
    char* p = (char*)d_ws;
    float* sums  = (float*)p;             p += 458752;      // 16*3584*2 f32
    float* stats = (float*)p;             p += 128;
    short* s1in  = (short*)p;             p += 1048576;     // [64][1024][8]
    short* s2in  = (short*)p;             p += 18874368;    // [128][1024][72]
    short* s3pad = (short*)p;             p += 54788096;    // [128][38][5632] pre-swizzled
    short* Bw3   = (short*)p;             p += 98304;       // [8][3][1][64][32]
    short* Bw5   = (short*)p;             p += 3932160;     // [8][5][12][128][32]
    short* Bw7   = (short*)p;             p += 27525120;    // [8][7][30][256][32]

    hipMemsetAsync(sums, 0, 458752, stream);
    hipMemsetAsync(s3pad, 0, 54788096, stream);
    prep_s1in<<<dim3(256), dim3(256), 0, stream>>>(x, s1in);
    prep_sx<<<dim3(512), dim3(256), 0, stream>>>(x, s2in, 72, 64);
    prep_s3x<<<dim3(512), dim3(256), 0, stream>>>(x, s3pad);
    wprep_d<3, 8, 4, 64, 1><<<dim3(24), dim3(256), 0, stream>>>(w3, Bw3);
    wprep_d<5, 72, 68, 128, 12><<<dim3(960), dim3(256), 0, stream>>>(w5, Bw5);
    wprep7c<<<dim3(1024), dim3(256), 0, stream>>>(w7, Bw7);

    conv_hk<3, 8, 64, 72, 0, true, false><<<dim3(512), dim3(512), 0, stream>>>(s1in, s2in, Bw3, b3, sums);
    conv_hk<5, 72, 128, 136, 64, false, true><<<dim3(512), dim3(512), 0, stream>>>(s2in, s3pad, Bw5, b5, sums);
    conv7_fused<<<dim3(512), dim3(512), 0, stream>>>(s3pad, Bw7, b7, sums);

    ln_stats<<<dim3(16), dim3(256), 0, stream>>>(sums, stats);
    head_gemv<<<dim3(960), dim3(256), 0, stream>>>(sums, stats, Wg, bg, gamma, beta, Wd, bd, out);
}

// Round 15
// 425.088 us; speedup vs baseline: 1.1003x; 1.0584x over previous
//
#include <hip/hip_runtime.h>
#include <math.h>

#define PI_F 3.14159265358979323846f

typedef short bf16x8 __attribute__((ext_vector_type(8)));
typedef float f32x4  __attribute__((ext_vector_type(4)));
typedef float f32x16 __attribute__((ext_vector_type(16)));

__device__ __forceinline__ short f2bf(float f) {
    union { float f; unsigned u; } v; v.f = f;
    unsigned r = v.u + 0x7fffu + ((v.u >> 16) & 1u);
    return (short)(r >> 16);
}

__device__ __forceinline__ void gld16(const short* g, short* l) {
    __builtin_amdgcn_global_load_lds(
        (const __attribute__((address_space(1))) unsigned int*)g,
        (__attribute__((address_space(3))) unsigned int*)l, 16, 0, 0);
}

// generic dense-K weight repack element
__device__ __forceinline__ void wprep_body(const float* __restrict__ w, short* __restrict__ Bw,
                                           int idx, int KS, int CHS, int CINR, int COUT, int NCH) {
    int kb = idx & 3;
    int r  = idx >> 2;
    int n  = r % COUT;  r /= COUT;
    int c  = r % NCH;   r /= NCH;
    int kh = r % KS;
    int br = r / KS;
    short v8[8];
    #pragma unroll
    for (int j = 0; j < 8; ++j) {
        int k   = c * 32 + kb * 8 + j;
        int kwc = k / CHS;
        int ch  = k - kwc * CHS;
        float f = (kwc < KS && ch < CINR)
                ? w[(((size_t)br * COUT + n) * CINR + ch) * (KS * KS) + kh * KS + kwc] : 0.f;
        v8[j] = f2bf(f);
    }
    *(int4*)(Bw + (size_t)idx * 8) = *(const int4*)v8;
}

// ---------------- mega_prep: all prep work in ONE launch (block-range dispatch) ----------
// R0 [0,112): sums zero. R1 [112,240): s3pad border/tail zero (1 pair/block).
// R2 [240,496): s1in. R3 [496,1008): s2in x-group. R4 [1008,1520): s3pad x-group.
// R5 [1520,1544): wprep3. R6 [1544,2504): wprep5. R7 [2504,3528): wprep7 (coalesced).
__global__ __launch_bounds__(256) void mega_prep(
    const float* __restrict__ x,  const float* __restrict__ w3,
    const float* __restrict__ w5, const float* __restrict__ w7,
    float* __restrict__ sums, short* __restrict__ s1in, short* __restrict__ s2in,
    short* __restrict__ s3pad, short* __restrict__ Bw3, short* __restrict__ Bw5,
    short* __restrict__ Bw7)
{
    __shared__ float lds[12936];
    int blk = blockIdx.x;
    const int t = threadIdx.x;

    if (blk < 112) {                       // sums = 0 (112*256*16B = 458,752B exactly)
        int idx = blk * 256 + t;
        *(float4*)((char*)sums + (size_t)idx * 16) = (float4){0.f, 0.f, 0.f, 0.f};
        return;
    }
    blk -= 112;
    if (blk < 128) {                       // s3pad borders+tails for pair=blk
        char* base = (char*)s3pad + (size_t)blk * 38 * 11264;
        const int4 z = {0, 0, 0, 0};
        for (int e = t; e < 6 * 704; e += 256) {          // full rows 0,1,2,35,36,37
            int rj = e / 704, ch = e - rj * 704;
            int row = (rj < 3) ? rj : (32 + rj);
            *(int4*)(base + (size_t)row * 11264 + ch * 16) = z;
        }
        for (int e = t; e < 32 * 160; e += 256) {         // interior rows: L/R cols + tail
            int row = 3 + e / 160, k = e % 160;
            size_t rb = (size_t)row * 11264;
            if (k < 51)       *(int4*)(base + rb + k * 16) = z;                 // bytes [0,816)
            else if (k < 102) *(int4*)(base + rb + 9520 + (k - 51) * 16) = z;   // [9520,10336)
            else              *(int4*)(base + rb + 10336 + (k - 102) * 16) = z; // [10336,11264)
        }
        return;
    }
    blk -= 128;
    if (blk < 256) {                       // s1in: [b][g][1024][8], ch4..7 = 0
        int idx = blk * 256 + t;
        int px = idx & 1023;
        int g  = (idx >> 10) & 3;
        int b  = idx >> 12;
        short v8[8];
        #pragma unroll
        for (int j = 0; j < 8; ++j) {
            float f = (j < 4) ? x[((b * 16 + g * 4 + j) << 10) + px] : 0.f;
            v8[j] = f2bf(f);
        }
        *(int4*)(s1in + (size_t)idx * 8) = *(const int4*)v8;
        return;
    }
    blk -= 256;
    if (blk < 512) {                       // s2in x-group at ch64..71
        int idx = blk * 256 + t;
        int px = idx & 1023, pair = idx >> 10;
        int i = pair >> 4, b = pair & 15, g = i >> 1;
        short v8[8];
        #pragma unroll
        for (int j = 0; j < 8; ++j) {
            float f = (j < 4) ? x[((b * 16 + g * 4 + j) << 10) + px] : 0.f;
            v8[j] = f2bf(f);
        }
        *(int4*)(s2in + (size_t)idx * 72 + 64) = *(const int4*)v8;
        return;
    }
    blk -= 512;
    if (blk < 512) {                       // s3pad x-group (pre-swizzled)
        int idx = blk * 256 + t;
        int px = idx & 1023, pair = idx >> 10;
        int i = pair >> 4, b = pair & 15, g = i >> 1;
        int R = px >> 5, C = px & 31;
        short v8[8];
        #pragma unroll
        for (int j = 0; j < 8; ++j) {
            float f = (j < 4) ? x[((b * 16 + g * 4 + j) << 10) + px] : 0.f;
            v8[j] = f2bf(f);
        }
        int p = ((C + 3) * 136 + 128) * 2;
        p ^= ((p >> 7) & 1) << 4;
        *(int4*)((char*)s3pad + ((size_t)pair * 38 + R + 3) * 11264 + p) = *(const int4*)v8;
        return;
    }
    blk -= 512;
    if (blk < 24) {                        // wprep3 (TOTAL 6144)
        int idx = blk * 256 + t;
        wprep_body(w3, Bw3, idx, 3, 8, 4, 64, 1);
        return;
    }
    blk -= 24;
    if (blk < 960) {                       // wprep5 (TOTAL 245760)
        int idx = blk * 256 + t;
        wprep_body(w5, Bw5, idx, 5, 72, 68, 128, 12);
        return;
    }
    blk -= 960;
    {                                      // wprep7 coalesced (1024 blocks)
        const int pairN = blk & 127;
        const int br    = blk >> 7;
        const int n0 = pairN * 2;
        const float* src = w7 + ((size_t)br * 256 + n0) * 6468;
        for (int e = t; e < 3234; e += 256)
            *(float4*)(lds + e * 4) = *(const float4*)(src + e * 4);
        __syncthreads();
        for (int e = t; e < 1680; e += 256) {
            int oct = e & 3;
            int r = e >> 2;
            int c  = r % 30; r /= 30;
            int kh = r % 7;
            int dn = r / 7;
            short v8[8];
            #pragma unroll
            for (int j = 0; j < 8; ++j) {
                int k = c * 32 + oct * 8 + j;
                int kwc = k / 136, ch = k - kwc * 136;
                float f = (kwc < 7 && ch < 132) ? lds[dn * 6468 + ch * 49 + kh * 7 + kwc] : 0.f;
                v8[j] = f2bf(f);
            }
            size_t dst = ((((size_t)br * 7 + kh) * 30 + c) * 256 + (n0 + dn)) * 32 + oct * 8;
            *(int4*)(Bw7 + dst) = *(const int4*)v8;
        }
    }
}

// ---------------- conv3/conv5: 16x16 path (round-12 structure, unchanged) ----------------
template<int KS, int CHS, int COUT, int CHS_OUT, int FOFF, bool S1SRC, bool POUT>
__global__ __launch_bounds__(512, 2) void conv_hk(
    const short* __restrict__ sIn,
    short* __restrict__ sOut,
    const short* __restrict__ Bw,
    const float* __restrict__ bias,
    float* __restrict__ sums)
{
    constexpr int PAD    = KS / 2;
    constexpr int NCH    = (KS * CHS + 31) / 32;
    constexpr int TCX    = 32 + (NCH * 32 - 1) / CHS;
    constexpr int NSLOT  = 9;
    constexpr int NFN    = COUT / 64;
    constexpr int CPP    = CHS / 8;
    constexpr int RCHK   = TCX * CPP;
    constexpr int CHUNKB = COUT * 32;
    static_assert(NCH == 1 || (NCH % 2) == 0, "NCH must be 1 or even");
    static_assert(RCHK <= 512, "single stg reg");

    __shared__ int4 AtileV[(NSLOT * TCX * CHS) / 8];
    short* Atile = (short*)AtileV;

    const int t    = threadIdx.x;
    const int lane = t & 63, w = t >> 6;
    const int wm = w >> 2, wn = w & 3;
    const int lm = lane & 15, kb = lane >> 4;

    const int bid = blockIdx.x;
    const int i  = bid & 7;
    const int b  = (bid >> 3) & 15;
    const int mt = bid >> 7;
    const int r0 = mt * 8;

    const int pairIdx = i * 16 + b;
    const int pairPx = pairIdx << 10;
    const int srcPx  = S1SRC ? ((b * 4 + (i >> 1)) << 10) : pairPx;

    int nIdx[NFN], nOff[NFN];
    #pragma unroll
    for (int fn = 0; fn < NFN; ++fn) {
        nIdx[fn] = wn * (COUT / 4) + fn * 16 + lm;
        nOff[fn] = nIdx[fn] * 32 + kb * 8;
    }

    f32x4 acc[8][NFN];
    #pragma unroll
    for (int fm = 0; fm < 8; ++fm)
        #pragma unroll
        for (int fn = 0; fn < NFN; ++fn)
            acc[fm][fn] = (f32x4){0.f, 0.f, 0.f, 0.f};

    const short* Bp = Bw + (size_t)i * KS * NCH * CHUNKB;
    bf16x8 b0[NFN], b1[NFN];
    #pragma unroll
    for (int fn = 0; fn < NFN; ++fn)
        b0[fn] = *(const bf16x8*)(Bp + nOff[fn]);

    for (int e = t; e < 9 * RCHK; e += 512) {
        int j  = e / RCHK, e2 = e - j * RCHK;
        int tc = e2 / CPP, kc = e2 - tc * CPP;
        int rin = r0 - PAD + j, cin = tc - PAD;
        int4 v = {0, 0, 0, 0};
        if (rin >= 0 && rin < 32 && cin >= 0 && cin < 32)
            v = *(const int4*)(sIn + (size_t)(srcPx + rin * 32 + cin) * CHS + kc * 8);
        *(int4*)(Atile + (j * TCX + tc) * CHS + kc * 8) = v;
    }
    __syncthreads();

    int aB[8];

    for (int kh = 0; kh < KS; ++kh) {
        #pragma unroll
        for (int fm = 0; fm < 8; ++fm) {
            int slot = kh + wm * 4 + (fm >> 1);
            if (slot >= NSLOT) slot -= NSLOT;
            aB[fm] = (slot * TCX + (fm & 1) * 16 + lm) * CHS + kb * 8;
        }

        const bool doStage = (kh <= KS - 3);
        const int stRin = r0 - PAD + kh + 9;
        int4 stg0 = {0, 0, 0, 0};
        if (doStage) {
            if (t < RCHK) {
                int tc = t / CPP, kc = t - tc * CPP;
                int cin = tc - PAD;
                if (stRin >= 0 && stRin < 32 && cin >= 0 && cin < 32)
                    stg0 = *(const int4*)(sIn + (size_t)(srcPx + stRin * 32 + cin) * CHS + kc * 8);
            }
        }

        if constexpr (NCH == 1) {
            __builtin_amdgcn_s_setprio(1);
            #pragma unroll
            for (int fm = 0; fm < 8; ++fm) {
                bf16x8 af = *(const bf16x8*)(Atile + aB[fm]);
                #pragma unroll
                for (int fn = 0; fn < NFN; ++fn)
                    acc[fm][fn] = __builtin_amdgcn_mfma_f32_16x16x32_bf16(af, b0[fn], acc[fm][fn], 0, 0, 0);
            }
            __builtin_amdgcn_s_setprio(0);
            if (kh < KS - 1) {
                #pragma unroll
                for (int fn = 0; fn < NFN; ++fn)
                    b0[fn] = *(const bf16x8*)(Bp + CHUNKB + nOff[fn]);
            }
            Bp += CHUNKB;
        } else {
            #pragma unroll 1
            for (int c = 0; c < NCH; c += 2) {
                #pragma unroll
                for (int fn = 0; fn < NFN; ++fn)
                    b1[fn] = *(const bf16x8*)(Bp + (size_t)(c + 1) * CHUNKB + nOff[fn]);
                __builtin_amdgcn_s_setprio(1);
                #pragma unroll
                for (int fm = 0; fm < 8; ++fm) {
                    bf16x8 af = *(const bf16x8*)(Atile + aB[fm] + c * 32);
                    #pragma unroll
                    for (int fn = 0; fn < NFN; ++fn)
                        acc[fm][fn] = __builtin_amdgcn_mfma_f32_16x16x32_bf16(af, b0[fn], acc[fm][fn], 0, 0, 0);
                }
                __builtin_amdgcn_s_setprio(0);
                if (!(kh == KS - 1 && c + 2 >= NCH)) {
                    #pragma unroll
                    for (int fn = 0; fn < NFN; ++fn)
                        b0[fn] = *(const bf16x8*)(Bp + (size_t)(c + 2) * CHUNKB + nOff[fn]);
                }
                __builtin_amdgcn_s_setprio(1);
                #pragma unroll
                for (int fm = 0; fm < 8; ++fm) {
                    bf16x8 af = *(const bf16x8*)(Atile + aB[fm] + (c + 1) * 32);
                    #pragma unroll
                    for (int fn = 0; fn < NFN; ++fn)
                        acc[fm][fn] = __builtin_amdgcn_mfma_f32_16x16x32_bf16(af, b1[fn], acc[fm][fn], 0, 0, 0);
                }
                __builtin_amdgcn_s_setprio(0);
            }
            Bp += (size_t)NCH * CHUNKB;
        }

        __syncthreads();
        if (doStage && t < RCHK) {
            int tc = t / CPP, kc = t - tc * CPP;
            *(int4*)(Atile + (kh * TCX + tc) * CHS + kc * 8) = stg0;
        }
    }

    float cwv[2][4];
    #pragma unroll
    for (int half = 0; half < 2; ++half)
        #pragma unroll
        for (int r = 0; r < 4; ++r)
            cwv[half][r] = cosf(PI_F * (half * 16 + kb * 4 + r + 0.5f) / 32.f);

    #pragma unroll
    for (int fn = 0; fn < NFN; ++fn) {
        int n = nIdx[fn];
        float bv = bias[i * COUT + n];
        float s0 = 0.f, s1 = 0.f;
        #pragma unroll
        for (int fm = 0; fm < 8; ++fm) {
            int imgrow = wm * 4 + (fm >> 1);
            int half = fm & 1;
            #pragma unroll
            for (int r = 0; r < 4; ++r) {
                float v = fmaxf(acc[fm][fn][r] + bv, 0.f);
                int col = half * 16 + kb * 4 + r;
                int R = r0 + imgrow;
                if constexpr (POUT) {
                    int p = ((col + 3) * CHS_OUT + n) * 2;
                    p ^= ((p >> 7) & 1) << 4;
                    *(short*)((char*)sOut + ((size_t)pairIdx * 38 + R + 3) * 11264 + p) = f2bf(v);
                } else if constexpr (CHS_OUT > 0) {
                    sOut[(size_t)(pairPx + R * 32 + col) * CHS_OUT + n] = f2bf(v);
                }
                s0 += v;
                s1 += v * cwv[half][r];
            }
        }
        s0 += __shfl_xor(s0, 16); s1 += __shfl_xor(s1, 16);
        s0 += __shfl_xor(s0, 32); s1 += __shfl_xor(s1, 32);
        if (kb == 0) {
            int ch = i * 448 + FOFF + n;
            atomicAdd(&sums[((size_t)b * 3584 + ch) * 2 + 0], s0);
            atomicAdd(&sums[((size_t)b * 3584 + ch) * 2 + 1], s1);
        }
    }
}

// ---------------- conv7: kh-fused (round-14 configuration, 70% MfmaUtil) ----------------
__global__ __launch_bounds__(512, 2) void conv7_fused(
    const short* __restrict__ sPad,   // [128][38][5632] shorts, pre-swizzled rows
    const short* __restrict__ Bw,     // [8][7][30][256][32]
    const float* __restrict__ bias,   // [8][256]
    float* __restrict__ sums)
{
    constexpr int NCH = 30, COUT = 256;
    constexpr int RSTR = 5632;
    constexpr int CHUNKB = COUT * 32;

    __shared__ int4 AldsV[(14 * RSTR) / 8];    // 157,696 B
    short* Alds = (short*)AldsV;

    const int t    = threadIdx.x;
    const int lane = t & 63, w = t >> 6;
    const int ln = lane & 31, hi = lane >> 5;

    const int bid = blockIdx.x;
    const int i  = bid & 7;
    const int b  = (bid >> 3) & 15;
    const int mt = bid >> 7;
    const int r0 = mt * 8;
    const size_t sBase = (size_t)(i * 16 + b) * 38 * RSTR;

    const int n = w * 32 + ln;
    const int nOffB = n * 32 + hi * 8;
    const int cstart = (w & 4) ? 15 : 0;       // desync SIMD-sharing waves

    f32x16 acc[8];
    #pragma unroll
    for (int ro = 0; ro < 8; ++ro) acc[ro] = (f32x16)(0.f);

    const short* BpI = Bw + (size_t)i * 7 * NCH * CHUNKB;

    for (int s = w; s < 154; s += 8) {
        int j = s / 11, sg = s - j * 11;
        gld16(sPad + sBase + (size_t)(r0 + j) * RSTR + sg * 512 + lane * 8,
              Alds + j * RSTR + sg * 512 + lane * 8);
    }
    bf16x8 bA[7], bB[7];
    #pragma unroll
    for (int kh = 0; kh < 7; ++kh)
        bA[kh] = *(const bf16x8*)(BpI + ((size_t)kh * NCH + cstart) * CHUNKB + nOffB);
    __syncthreads();

    auto HALF = [&](bf16x8 (&bq)[7], int c, int kk) {
        int swb = ln * 272 + c * 64 + kk * 32 + hi * 16;
        swb ^= ((swb >> 7) & 1) << 4;
        __builtin_amdgcn_s_setprio(1);
        #pragma unroll
        for (int j = 0; j < 14; ++j) {
            bf16x8 af = *(const bf16x8*)((const char*)Alds + j * 11264 + swb);
            const int klo = (j > 7) ? (j - 7) : 0;
            const int khi = (j < 6) ? j : 6;
            #pragma unroll
            for (int kh = klo; kh <= khi; ++kh)
                acc[j - kh] = __builtin_amdgcn_mfma_f32_32x32x16_bf16(af, bq[kh], acc[j - kh], 0, 0, 0);
        }
        __builtin_amdgcn_s_setprio(0);
    };

    #pragma unroll 1
    for (int ci = 0; ci < NCH; ++ci) {
        int cc = cstart + ci; if (cc >= NCH) cc -= NCH;
        int cn = cc + 1;      if (cn >= NCH) cn -= NCH;
        #pragma unroll
        for (int kh = 0; kh < 7; ++kh)
            bB[kh] = *(const bf16x8*)(BpI + ((size_t)kh * NCH + cc) * CHUNKB + nOffB + 16);
        HALF(bA, cc, 0);
        if (ci + 1 < NCH) {
            #pragma unroll
            for (int kh = 0; kh < 7; ++kh)
                bA[kh] = *(const bf16x8*)(BpI + ((size_t)kh * NCH + cn) * CHUNKB + nOffB);
        }
        HALF(bB, cc, 1);
    }

    float cw[16];
    #pragma unroll
    for (int r = 0; r < 16; ++r) {
        int px = (r & 3) + 8 * (r >> 2) + 4 * hi;
        cw[r] = cosf(PI_F * (px + 0.5f) / 32.f);
    }

    float bv = bias[i * COUT + n];
    float s0 = 0.f, s1 = 0.f;
    #pragma unroll
    for (int ro = 0; ro < 8; ++ro) {
        #pragma unroll
        for (int r = 0; r < 16; ++r) {
            float v = fmaxf(acc[ro][r] + bv, 0.f);
            s0 += v;
            s1 += v * cw[r];
        }
    }
    s0 += __shfl_xor(s0, 32);
    s1 += __shfl_xor(s1, 32);
    if (hi == 0) {
        int ch = i * 448 + 192 + n;
        atomicAdd(&sums[((size_t)b * 3584 + ch) * 2 + 0], s0);
        atomicAdd(&sums[((size_t)b * 3584 + ch) * 2 + 1], s1);
    }
}

// ---------------- head: LN stats + parallel GEMV ----------------
__global__ __launch_bounds__(256) void ln_stats(const float* __restrict__ sums,
                                                float* __restrict__ stats) {
    __shared__ float red[8];
    const int b = blockIdx.x;
    const int t = threadIdx.x, lane = t & 63, wv = t >> 6;
    const float* S = sums + (size_t)b * 7168;
    float ls = 0.f, lq = 0.f;
    for (int f = t; f < 7168; f += 256) { float v = S[f]; ls += v; lq += v * v; }
    for (int m = 1; m < 64; m <<= 1) { ls += __shfl_xor(ls, m); lq += __shfl_xor(lq, m); }
    if (lane == 0) { red[wv] = ls; red[4 + wv] = lq; }
    __syncthreads();
    if (t == 0) {
        float ts = red[0] + red[1] + red[2] + red[3];
        float tq = red[4] + red[5] + red[6] + red[7];
        float mu  = ts * (1.f / 7168.f);
        float var = tq * (1.f / 7168.f) - mu * mu;
        stats[b * 2 + 0] = mu;
        stats[b * 2 + 1] = rsqrtf(var + 1e-5f);
    }
}

__global__ __launch_bounds__(256) void head_gemv(
    const float* __restrict__ sums,
    const float* __restrict__ stats,
    const float* __restrict__ Wg, const float* __restrict__ bg,
    const float* __restrict__ gamma, const float* __restrict__ beta,
    const float* __restrict__ Wd, const float* __restrict__ bd,
    float* __restrict__ out)
{
    __shared__ float red[8];
    const int n = blockIdx.x % 60;
    const int b = blockIdx.x / 60;
    const int t = threadIdx.x, lane = t & 63, wv = t >> 6;
    const float* S  = sums + (size_t)b * 7168;
    const float mu  = stats[b * 2 + 0];
    const float inv = stats[b * 2 + 1];

    const float* wd = Wd + (size_t)n * 7168;
    float accd = 0.f;
    for (int f = t; f < 7168; f += 256) {
        float v = (S[f] - mu) * inv * gamma[f] + beta[f];
        accd = fmaf(v, wd[f], accd);
    }
    const float* wg = Wg + (size_t)n * 3584;
    float accg = 0.f;
    for (int ch = t; ch < 3584; ch += 256)
        accg = fmaf(S[2 * ch], wg[ch], accg);

    for (int m = 1; m < 64; m <<= 1) { accg += __shfl_xor(accg, m); accd += __shfl_xor(accd, m); }
    if (lane == 0) { red[wv] = accg; red[4 + wv] = accd; }
    __syncthreads();
    if (t == 0) {
        float g = red[0] + red[1] + red[2] + red[3];
        float d = red[4] + red[5] + red[6] + red[7];
        out[b * 60 + n]       = g * (1.f / 1024.f) + bg[n];
        out[960 + b * 60 + n] = d + bd[n];
    }
}

extern "C" void kernel_launch(void* const* d_in, const int* in_sizes, int n_in,
                              void* d_out, int out_size, void* d_ws, size_t ws_size,
                              hipStream_t stream)
{
    const float* x     = (const float*)d_in[0];
    const float* w3    = (const float*)d_in[1];
    const float* b3    = (const float*)d_in[2];
    const float* w5    = (const float*)d_in[3];
    const float* b5    = (const float*)d_in[4];
    const float* w7    = (const float*)d_in[5];
    const float* b7    = (const float*)d_in[6];
    const float* Wg    = (const float*)d_in[7];
    const float* bg    = (const float*)d_in[8];
    const float* gamma = (const float*)d_in[9];
    const float* beta  = (const float*)d_in[10];
    const float* Wd    = (const float*)d_in[11];
    const float* bd    = (const float*)d_in[12];
    float* out = (float*)d_out;

    // workspace layout (bytes) — round-12 proven layout
    char* p = (char*)d_ws;
    float* sums  = (float*)p;             p += 458752;      // 16*3584*2 f32
    float* stats = (float*)p;             p += 128;
    short* s1in  = (short*)p;             p += 1048576;     // [64][1024][8]
    short* s2in  = (short*)p;             p += 18874368;    // [128][1024][72]
    short* s3pad = (short*)p;             p += 54788096;    // [128][38][5632] pre-swizzled
    short* Bw3   = (short*)p;             p += 98304;       // [8][3][1][64][32]
    short* Bw5   = (short*)p;             p += 3932160;     // [8][5][12][128][32]
    short* Bw7   = (short*)p;             p += 27525120;    // [8][7][30][256][32]

    mega_prep<<<dim3(3528), dim3(256), 0, stream>>>(x, w3, w5, w7,
        sums, s1in, s2in, s3pad, Bw3, Bw5, Bw7);

    conv_hk<3, 8, 64, 72, 0, true, false><<<dim3(512), dim3(512), 0, stream>>>(s1in, s2in, Bw3, b3, sums);
    conv_hk<5, 72, 128, 136, 64, false, true><<<dim3(512), dim3(512), 0, stream>>>(s2in, s3pad, Bw5, b5, sums);
    conv7_fused<<<dim3(512), dim3(512), 0, stream>>>(s3pad, Bw7, b7, sums);

    ln_stats<<<dim3(16), dim3(256), 0, stream>>>(sums, stats);
    head_gemv<<<dim3(960), dim3(256), 0, stream>>>(sums, stats, Wg, bg, gamma, beta, Wd, bd, out);
}